// Round 1
// baseline (75.603 us; speedup 1.0000x reference)
//
#include <hip/hip_runtime.h>
#include <hip/hip_bf16.h>

// N=8192 rows, D=128. loss = mean(-log(exp(sims_ii)) + 0.5*(log(den_i)+log(den_j)))
// sims = (A @ T^T) * exp(temp); den = row/col sums of exp(sims) with diag zeroed.
//
// ws layout (bytes):
//   [0,       2 MiB)  A bf16, XOR-swizzled chunks   (ushort[8192][128])
//   [2 MiB,   4 MiB)  T bf16, XOR-swizzled chunks
//   [4 MiB,   8 MiB)  den_i partials float[128][8192]  (slot = bj*2+wc)
//   [8 MiB,  12 MiB)  den_j partials float[128][8192]  (slot = bi*2+wr)
//   [12 MiB, +32 KiB) per-row loss float[8192]

typedef __attribute__((ext_vector_type(8))) __bf16 bf16x8;
typedef __attribute__((ext_vector_type(4))) float  f32x4;

#define GLD16(g, l) __builtin_amdgcn_global_load_lds(                         \
    (const __attribute__((address_space(1))) unsigned int*)(const void*)(g),  \
    (__attribute__((address_space(3))) unsigned int*)(void*)(l), 16, 0, 0)

__device__ __forceinline__ ushort f2bf(float f) {
    union { float f; unsigned u; } v; v.f = f;
    unsigned r = v.u + 0x7fffu + ((v.u >> 16) & 1u);   // RNE (finite inputs)
    return (ushort)(r >> 16);
}

// ---------------------------------------------------------------- kernel 1
// One thread = one 8-element chunk. Swizzle: chunk c of row r lands at c^(r&7)
// (byte ^= (r&7)<<4), so GEMM stages linearly and ds_reads with the same XOR.
__global__ void convert_swizzle(const float* __restrict__ a,
                                const float* __restrict__ t,
                                ushort* __restrict__ oa,
                                ushort* __restrict__ ot) {
    int idx = blockIdx.x * 256 + threadIdx.x;          // 0 .. 262143
    const float* src = (idx >> 17) ? t : a;
    ushort*      dst = (idx >> 17) ? ot : oa;
    int loc = idx & 131071;
    int r = loc >> 4;
    int c = loc & 15;
    const float4* s4 = reinterpret_cast<const float4*>(src + r * 128 + c * 8);
    float4 f0 = s4[0], f1 = s4[1];
    uint4 o;
    o.x = f2bf(f0.x) | ((unsigned)f2bf(f0.y) << 16);
    o.y = f2bf(f0.z) | ((unsigned)f2bf(f0.w) << 16);
    o.z = f2bf(f1.x) | ((unsigned)f2bf(f1.y) << 16);
    o.w = f2bf(f1.z) | ((unsigned)f2bf(f1.w) << 16);
    *reinterpret_cast<uint4*>(dst + r * 128 + ((c ^ (r & 7)) << 3)) = o;
}

// ---------------------------------------------------------------- kernel 2
// 128x128 tile per block, 4 waves (2x2), K=128 in a single staging pass.
// Epilogue: exp(scale*sim), per-tile row sums -> Pi[slot][row],
// col sums -> Pj[slot][col]; every slot written exactly once (deterministic).
__global__ void __launch_bounds__(256)
gemm_exp(const ushort* __restrict__ Ab, const ushort* __restrict__ Tb,
         const float* __restrict__ temps,
         float* __restrict__ Pi, float* __restrict__ Pj) {
    __shared__ ushort ldsA[128 * 128];
    __shared__ ushort ldsB[128 * 128];
    const int bi = blockIdx.x, bj = blockIdx.y;
    const int tid = threadIdx.x;
    const int wave = tid >> 6, lane = tid & 63;
    const int wr = wave >> 1, wc = wave & 1;
    const int krow = lane >> 4, lcol = lane & 15;

    const ushort* ga = Ab + bi * 16384;   // tile = contiguous 32 KiB (swizzled)
    const ushort* gb = Tb + bj * 16384;
#pragma unroll
    for (int rnd = 0; rnd < 8; ++rnd) {
        int c = rnd * 256 + wave * 64;    // wave-uniform chunk base; HW adds lane*16B
        GLD16(ga + (c + lane) * 8, ldsA + c * 8);
        GLD16(gb + (c + lane) * 8, ldsB + c * 8);
    }
    __syncthreads();

    f32x4 acc[4][4];
#pragma unroll
    for (int m = 0; m < 4; ++m)
#pragma unroll
        for (int n = 0; n < 4; ++n)
            acc[m][n] = (f32x4){0.f, 0.f, 0.f, 0.f};

#pragma unroll
    for (int kk = 0; kk < 4; ++kk) {
        const int k0 = kk * 32 + krow * 8;
        bf16x8 af[4], bfr[4];
#pragma unroll
        for (int m = 0; m < 4; ++m) {
            int ra = wr * 64 + m * 16 + lcol;
            af[m] = *reinterpret_cast<const bf16x8*>(&ldsA[ra * 128 + (k0 ^ ((ra & 7) << 3))]);
        }
#pragma unroll
        for (int n = 0; n < 4; ++n) {
            int rb = wc * 64 + n * 16 + lcol;
            bfr[n] = *reinterpret_cast<const bf16x8*>(&ldsB[rb * 128 + (k0 ^ ((rb & 7) << 3))]);
        }
#pragma unroll
        for (int m = 0; m < 4; ++m)
#pragma unroll
            for (int n = 0; n < 4; ++n)
                acc[m][n] = __builtin_amdgcn_mfma_f32_16x16x32_bf16(af[m], bfr[n], acc[m][n], 0, 0, 0);
    }

    // ---- epilogue: exp + row/col partial sums ----
    const float sc = __expf(temps[0]);
    float rsum[4][4];
    float csum[4] = {0.f, 0.f, 0.f, 0.f};
#pragma unroll
    for (int m = 0; m < 4; ++m)
#pragma unroll
        for (int j = 0; j < 4; ++j) rsum[m][j] = 0.f;

#pragma unroll
    for (int m = 0; m < 4; ++m)
#pragma unroll
        for (int n = 0; n < 4; ++n)
#pragma unroll
            for (int j = 0; j < 4; ++j) {
                float v = __expf(acc[m][n][j] * sc);
                rsum[m][j] += v;
                csum[n] += v;
            }

    // row sums: D layout row=(lane>>4)*4+j, col=lane&15 -> reduce lanes 0..15
#pragma unroll
    for (int m = 0; m < 4; ++m)
#pragma unroll
        for (int j = 0; j < 4; ++j) {
            float v = rsum[m][j];
            v += __shfl_xor(v, 1); v += __shfl_xor(v, 2);
            v += __shfl_xor(v, 4); v += __shfl_xor(v, 8);
            if (lcol == 0) {
                int row = bi * 128 + wr * 64 + m * 16 + krow * 4 + j;
                Pi[(bj * 2 + wc) * 8192 + row] = v;
            }
        }
    // col sums: reduce across krow groups (lanes l, l^16, l^32, l^48)
#pragma unroll
    for (int n = 0; n < 4; ++n) {
        float v = csum[n];
        v += __shfl_xor(v, 16); v += __shfl_xor(v, 32);
        if (lane < 16) {
            int col = bj * 128 + wc * 64 + n * 16 + lane;
            Pj[(bi * 2 + wr) * 8192 + col] = v;
        }
    }
}

// ---------------------------------------------------------------- kernel 3
// One wave per row: fp32-precise diag dot; den = sum(partials) - exp(sc*dot).
__global__ void finalize_rows(const float* __restrict__ a, const float* __restrict__ t,
                              const float* __restrict__ temps,
                              const float* __restrict__ Pi, const float* __restrict__ Pj,
                              float* __restrict__ loss) {
    const int r = blockIdx.x;
    const int l = threadIdx.x;   // 0..63
    const float sc = __expf(temps[0]);
    float deni = Pi[l * 8192 + r] + Pi[(l + 64) * 8192 + r];
    float denj = Pj[l * 8192 + r] + Pj[(l + 64) * 8192 + r];
    float dotp = a[r * 128 + l] * t[r * 128 + l]
               + a[r * 128 + 64 + l] * t[r * 128 + 64 + l];
#pragma unroll
    for (int m = 1; m < 64; m <<= 1) {
        deni += __shfl_xor(deni, m);
        denj += __shfl_xor(denj, m);
        dotp += __shfl_xor(dotp, m);
    }
    if (l == 0) {
        float diag = __expf(sc * dotp);
        float di = fmaxf(deni - diag, 1e-20f);
        float dj = fmaxf(denj - diag, 1e-20f);
        loss[r] = -sc * dotp + 0.5f * (__logf(di) + __logf(dj));
    }
}

// ---------------------------------------------------------------- kernel 4
__global__ void reduce_loss(const float* __restrict__ loss, float* __restrict__ out) {
    __shared__ float wsum[4];
    const int tid = threadIdx.x;   // 256
    float s = 0.f;
#pragma unroll
    for (int i = 0; i < 32; ++i) s += loss[tid + i * 256];
#pragma unroll
    for (int m = 1; m < 64; m <<= 1) s += __shfl_xor(s, m);
    if ((tid & 63) == 0) wsum[tid >> 6] = s;
    __syncthreads();
    if (tid == 0) out[0] = (wsum[0] + wsum[1] + wsum[2] + wsum[3]) * (1.0f / 8192.0f);
}

extern "C" void kernel_launch(void* const* d_in, const int* in_sizes, int n_in,
                              void* d_out, int out_size, void* d_ws, size_t ws_size,
                              hipStream_t stream) {
    const float* a     = (const float*)d_in[0];
    const float* t     = (const float*)d_in[1];
    const float* temps = (const float*)d_in[2];
    float* out = (float*)d_out;

    char* ws = (char*)d_ws;
    ushort* Ab  = (ushort*)(ws);
    ushort* Tb  = (ushort*)(ws + (2u << 20));
    float*  Pi  = (float*)(ws + (4u << 20));
    float*  Pj  = (float*)(ws + (8u << 20));
    float*  los = (float*)(ws + (12u << 20));

    convert_swizzle<<<1024, 256, 0, stream>>>(a, t, Ab, Tb);
    gemm_exp<<<dim3(64, 64), 256, 0, stream>>>(Ab, Tb, temps, Pi, Pj);
    finalize_rows<<<8192, 64, 0, stream>>>(a, t, temps, Pi, Pj, los);
    reduce_loss<<<1, 256, 0, stream>>>(los, out);
}